// Round 14
// baseline (3382.804 us; speedup 1.0000x reference)
//
#include <hip/hip_runtime.h>
#include <cstdint>
#include <cstddef>

#define B_   64
#define T_   512
#define E_   512
#define H_   1024
#define G4_  4096
#define KTOT 1536
#define NWG  256

typedef float f32x4 __attribute__((ext_vector_type(4)));
typedef int   i32x4 __attribute__((ext_vector_type(4)));

#define OFF_XE    ((size_t)0)
#define OFF_WC    (OFF_XE + (size_t)T_*B_*E_*2)     // 32 MB
#define OFF_BIAS  (OFF_WC + (size_t)G4_*KTOT*2)     // +12.6 MB
#define OFF_H0    (OFF_BIAS + (size_t)G4_*4)
#define OFF_FLAGS (OFF_H0 + (size_t)B_*H_*2)
#define OFF_HBT   (OFF_FLAGS + (size_t)16384)       // bf16 h history, 64 MB

__device__ __forceinline__ unsigned short f2b(float f) {
    unsigned u = __float_as_uint(f);
    return (unsigned short)((u + 0x7fffu + ((u >> 16) & 1u)) >> 16);  // RNE
}

// Permuted weights, gate-interleaved within 16-col tiles:
// p = s*64 + w*16 + hd_l*4 + q  <->  orig row q*1024 + s*16 + w*4 + hd_l.
// (s: WG gate-block, w: wave, hd_l: hdim within wave, q: gate i,f,g,o)
__global__ void prep_w(const float* __restrict__ wih, const float* __restrict__ whh,
                       const float* __restrict__ bih, const float* __restrict__ bhh,
                       unsigned short* __restrict__ Wc, float* __restrict__ bp) {
    int p = blockIdx.x;
    int s = p >> 6, w = (p >> 4) & 3, hd_l = (p >> 2) & 3, q = p & 3;
    int orig = q * H_ + s * 16 + w * 4 + hd_l;
    unsigned short* dst = Wc + (size_t)p * KTOT;
    const float* s1 = wih + (size_t)orig * E_;
    const float* s2 = whh + (size_t)orig * H_;
    int tx = threadIdx.x;
#pragma unroll
    for (int i = 0; i < 2; ++i) dst[tx + i*256] = f2b(s1[tx + i*256]);
#pragma unroll
    for (int i = 0; i < 4; ++i) dst[E_ + tx + i*256] = f2b(s2[tx + i*256]);
    if (tx == 0) bp[p] = bih[orig] + bhh[orig];
}

__global__ void prep_xe(const int* __restrict__ x, const float* __restrict__ emb,
                        unsigned short* __restrict__ xe) {
    int bid = blockIdx.x;
    int t = bid >> 6, b = bid & 63;
    int idx = x[b * T_ + t];
    const float* src = emb + (size_t)idx * E_;
    unsigned short* dst = xe + ((size_t)t * B_ + b) * E_;
    int tx = threadIdx.x;
    dst[tx] = f2b(src[tx]);
    dst[tx + 256] = f2b(src[tx + 256]);
}

__global__ void prep_h(const float* __restrict__ h0, unsigned short* __restrict__ hb) {
    int b = blockIdx.x;
#pragma unroll
    for (int i = 0; i < 4; ++i) {
        int j = threadIdx.x + i*256;
        hb[(size_t)b * H_ + j] = f2b(h0[(size_t)b * H_ + j]);
    }
}

// v4: wave-autonomous. 256 WGs = 4 groups of 64 (g = wg&3 owns rows
// [16g,16g+16); s = wg>>2). Each of 4 waves owns 16 gate-interleaved cols
// (4 hdims x 4 gates) x FULL K=1536 -> complete gate sums per wave -> cell
// is wave-local (LDS bounce, no barrier). Each wave stores its own bf16 h
// (sc-bypass), acks own vmcnt, lane0 arrives (32 arrivals/subline/step).
// Wave0 polls 8 sublines; siblings spin on a volatile LDS token.
// ZERO __syncthreads in the loop.
__global__ __launch_bounds__(256, 1)
void lstm_v4(const unsigned short* __restrict__ xe,
             const unsigned short* __restrict__ Wc,
             const float* __restrict__ bp,
             const float* __restrict__ c0,
             const unsigned short* __restrict__ hb0,
             unsigned short* __restrict__ hbt,
             float* __restrict__ out,
             int* __restrict__ flags) {
    __shared__ float gp[4][16][20];      // per-wave gate slab, 16B-aligned rows
    __shared__ int sh_step;
    __shared__ int sh_dead;

    const int tid = threadIdx.x;
    const int wg  = blockIdx.x;
    const int g   = wg & 3;
    const int s   = wg >> 2;
    const int w = tid >> 6, l = tid & 63;
    const int lc = l & 15;
    const int lk = (l >> 4) << 3;

    if (tid == 0) { sh_step = 0; sh_dead = 0; }

    // ---- weights: 48 frags (full K), col = s*64 + w*16 + lc, AGPR-resident ----
    i32x4 wreg[48];
    {
        const unsigned short* wrow =
            Wc + (size_t)((s << 6) + (w << 4) + lc) * KTOT + lk;
#pragma unroll
        for (int f = 0; f < 48; ++f) wreg[f] = *(const i32x4*)(wrow + f * 32);
    }

    const int brow = (g << 4) + lc;      // A-operand batch row this lane loads

    // ---- cell identity: lane -> (row, hdim) bijective in (l>>4, l&3, (l&15)>>2) ----
    const int r_loc = ((l >> 4) << 2) + (l & 3);
    const int bglob = (g << 4) + r_loc;
    const int hd_l = (l & 15) >> 2;
    const int hdim = (s << 4) + (w << 2) + hd_l;
    float c = c0[(size_t)bglob * H_ + hdim];
    const int bbase = (s << 6) + (w << 4) + (hd_l << 2);
    const float bi  = bp[bbase];
    const float bf_ = bp[bbase + 1];
    const float bg  = bp[bbase + 2];
    const float bo  = bp[bbase + 3];

    int* subc = &flags[g << 10];         // 8 sub-counters, 128 B apart
    const int si = s & 7;

    i32x4 ax[16], ah[16];
    {   // t=0 xe frags
        const unsigned short* xp = xe + (size_t)brow * E_ + lk;
#pragma unroll
        for (int f = 0; f < 16; ++f) ax[f] = *(const i32x4*)(xp + f * 32);
    }
    __syncthreads();                     // once: sh_step/sh_dead init visible

    for (int t = 0; t < T_; ++t) {
        // ---- wait h(t-1): wave0 polls MALL, siblings spin on LDS token ----
        if (t > 0) {
            if (w == 0) {
                int dead = 0;
                const int tgt = t << 5;              // 32*t, monotonic
                unsigned spin = 0;
                for (;;) {
                    int v = (l < 8)
                        ? __hip_atomic_load(&subc[l << 5], __ATOMIC_RELAXED,
                                            __HIP_MEMORY_SCOPE_AGENT)
                        : tgt;
                    if (__all(v >= tgt)) break;
                    if (++spin > (1u << 17)) { dead = 1; break; }
                }
                if (l == 0) {
                    if (dead) *(volatile int*)&sh_dead = 1;
                    *(volatile int*)&sh_step = t;
                }
            } else {
                unsigned spin = 0;
                while (*(volatile int*)&sh_step < t)
                    if (++spin > (1u << 20)) break;  // escape, no hang
            }
            if (*(volatile int*)&sh_dead) break;
            asm volatile("" ::: "memory");           // pulls can't hoist above
        }

        const unsigned short* hsrc =
            (t == 0) ? (hb0 + (size_t)brow * H_ + lk)
                     : (hbt + (size_t)(t - 1) * (B_ * H_) + (size_t)brow * H_ + lk);
        // ---- pull h lo (dims 0..511) ----
#pragma unroll
        for (int f = 0; f < 16; ++f) ah[f] = *(const i32x4*)(hsrc + f * 32);

        f32x4 accA = {0.f, 0.f, 0.f, 0.f};
        f32x4 accB = {0.f, 0.f, 0.f, 0.f};
        // ---- xe chain (frags 0..15 -> accA), overlaps h-lo flight ----
        asm volatile("s_nop 3\n\tv_mfma_f32_16x16x32_bf16 %0, %1, %2, %0"
                     : "+v"(accA) : "v"(ax[0]), "a"(wreg[0]));
#pragma unroll
        for (int f = 1; f < 16; ++f)
            asm volatile("s_nop 1\n\tv_mfma_f32_16x16x32_bf16 %0, %1, %2, %0"
                         : "+v"(accA) : "v"(ax[f]), "a"(wreg[f]));
        // ---- pull h hi (dims 512..1023) into ax (xe consumed) ----
#pragma unroll
        for (int f = 0; f < 16; ++f) ax[f] = *(const i32x4*)(hsrc + 512 + f * 32);
        // ---- h-lo MFMAs: frags 16..23 -> accA, 24..31 -> accB (interleaved) ----
        asm volatile("s_nop 3\n\tv_mfma_f32_16x16x32_bf16 %0, %1, %2, %0"
                     : "+v"(accB) : "v"(ah[8]), "a"(wreg[24]));
#pragma unroll
        for (int j = 0; j < 8; ++j) {
            asm volatile("s_nop 1\n\tv_mfma_f32_16x16x32_bf16 %0, %1, %2, %0"
                         : "+v"(accA) : "v"(ah[j]), "a"(wreg[16 + j]));
            if (j)
                asm volatile("s_nop 1\n\tv_mfma_f32_16x16x32_bf16 %0, %1, %2, %0"
                             : "+v"(accB) : "v"(ah[8 + j]), "a"(wreg[24 + j]));
        }
        // ---- h-hi MFMAs: frags 32..47 -> accB ----
#pragma unroll
        for (int f = 0; f < 16; ++f)
            asm volatile("s_nop 1\n\tv_mfma_f32_16x16x32_bf16 %0, %1, %2, %0"
                         : "+v"(accB) : "v"(ax[f]), "a"(wreg[32 + f]));
        asm volatile("s_nop 7\n\ts_nop 7\n\ts_nop 7"
                     : "+v"(accA), "+v"(accB) :: "memory");  // MFMA -> read D
        f32x4 acc = accA + accB;         // K-halves sum (same split as v2)

        // ---- wave-local gate transpose through private LDS slab ----
        {
            const int r0 = (l >> 4) << 2;
#pragma unroll
            for (int j = 0; j < 4; ++j) gp[w][r0 + j][lc] = acc[j];
        }
        asm volatile("s_waitcnt lgkmcnt(0)" ::: "memory");
        __builtin_amdgcn_sched_barrier(0);
        f32x4 gt = *(const f32x4*)&gp[w][r_loc][hd_l << 2];  // [i,f,g,o]

        // ---- LSTM cell (one (row,hdim) per lane) ----
        float hv;
        {
            float xi = gt[0] + bi;
            float xf = gt[1] + bf_;
            float xg = gt[2] + bg;
            float xo = gt[3] + bo;
            float iv = 1.f / (1.f + __expf(-xi));
            float fv = 1.f / (1.f + __expf(-xf));
            float eg = __expf(2.f * fminf(fmaxf(xg, -15.f), 15.f));
            float gv = (eg - 1.f) / (eg + 1.f);
            float ov = 1.f / (1.f + __expf(-xo));
            c = fv * c + iv * gv;
            float ec = __expf(2.f * fminf(fmaxf(c, -15.f), 15.f));
            float th = (ec - 1.f) / (ec + 1.f);
            hv = ov * th;
        }
        const size_t oidx = ((size_t)bglob * T_ + t) * H_ + hdim;

        if (t < T_ - 1) {
            // bf16 h broadcast (bypass), own-wave ack, lane0 arrival
            unsigned long long ha = (unsigned long long)
                (hbt + (size_t)t * (B_ * H_) + (size_t)bglob * H_ + hdim);
            unsigned hval = (unsigned)f2b(hv);
            asm volatile("global_store_short %0, %1, off sc0 sc1"
                         :: "v"(ha), "v"(hval) : "memory");
            asm volatile("s_waitcnt vmcnt(0)" ::: "memory");
            if (l == 0)
                __hip_atomic_fetch_add(&subc[si << 5], 1, __ATOMIC_RELAXED,
                                       __HIP_MEMORY_SCOPE_AGENT);
            // off-critical-path: f32 out + xe(t+1) prefetch float over the poll
            __builtin_nontemporal_store(hv, &out[oidx]);
            {
                const unsigned short* xp =
                    xe + ((size_t)(t + 1) * B_ + brow) * E_ + lk;
#pragma unroll
                for (int f = 0; f < 16; ++f) ax[f] = *(const i32x4*)(xp + f * 32);
            }
        } else {
            __builtin_nontemporal_store(hv, &out[oidx]);
        }
    }
}

extern "C" void kernel_launch(void* const* d_in, const int* in_sizes, int n_in,
                              void* d_out, int out_size, void* d_ws, size_t ws_size,
                              hipStream_t stream) {
    const int*   x   = (const int*)  d_in[0];
    const float* emb = (const float*)d_in[1];
    const float* wih = (const float*)d_in[2];
    const float* whh = (const float*)d_in[3];
    const float* bih = (const float*)d_in[4];
    const float* bhh = (const float*)d_in[5];
    const float* h0  = (const float*)d_in[6];
    const float* c0  = (const float*)d_in[7];
    float* out = (float*)d_out;
    char* ws = (char*)d_ws;

    unsigned short* xe  = (unsigned short*)(ws + OFF_XE);
    unsigned short* Wc  = (unsigned short*)(ws + OFF_WC);
    float*          bp  = (float*)(ws + OFF_BIAS);
    unsigned short* hb0 = (unsigned short*)(ws + OFF_H0);
    int*            flg = (int*)(ws + OFF_FLAGS);
    unsigned short* hbt = (unsigned short*)(ws + OFF_HBT);

    (void)hipMemsetAsync(flg, 0, 4096 * sizeof(int), stream);
    prep_w <<<dim3(G4_),   dim3(256), 0, stream>>>(wih, whh, bih, bhh, Wc, bp);
    prep_xe<<<dim3(B_*T_), dim3(256), 0, stream>>>(x, emb, xe);
    prep_h <<<dim3(B_),    dim3(256), 0, stream>>>(h0, hb0);

    lstm_v4<<<dim3(NWG), dim3(256), 0, stream>>>(xe, Wc, bp, c0, hb0, hbt, out, flg);
}

// Round 15
// 2116.310 us; speedup vs baseline: 1.5984x; 1.5984x over previous
//
#include <hip/hip_runtime.h>
#include <cstdint>
#include <cstddef>

#define B_   64
#define T_   512
#define E_   512
#define H_   1024
#define G4_  4096
#define KTOT 1536
#define NWG  256

typedef float f32x4 __attribute__((ext_vector_type(4)));
typedef int   i32x4 __attribute__((ext_vector_type(4)));

#define OFF_XE    ((size_t)0)
#define OFF_WC    (OFF_XE + (size_t)T_*B_*E_*2)     // 32 MB
#define OFF_BIAS  (OFF_WC + (size_t)G4_*KTOT*2)     // +12.6 MB
#define OFF_H0    (OFF_BIAS + (size_t)G4_*4)
#define OFF_FLAGS (OFF_H0 + (size_t)B_*H_*2)
#define OFF_HBT   (OFF_FLAGS + (size_t)16384)       // bf16 h history, 64 MB

__device__ __forceinline__ unsigned short f2b(float f) {
    unsigned u = __float_as_uint(f);
    return (unsigned short)((u + 0x7fffu + ((u >> 16) & 1u)) >> 16);  // RNE
}

// Permuted combined weights: permuted row p = s*64 + q*16 + hl  <->
// original gate row q*1024 + s*16 + hl (q: i,f,g,o; s: 16-hdim block).
__global__ void prep_w(const float* __restrict__ wih, const float* __restrict__ whh,
                       const float* __restrict__ bih, const float* __restrict__ bhh,
                       unsigned short* __restrict__ Wc, float* __restrict__ bp) {
    int p = blockIdx.x;
    int s = p >> 6, q = (p >> 4) & 3, hl = p & 15;
    int orig = q * H_ + s * 16 + hl;
    unsigned short* dst = Wc + (size_t)p * KTOT;
    const float* s1 = wih + (size_t)orig * E_;
    const float* s2 = whh + (size_t)orig * H_;
    int tx = threadIdx.x;
#pragma unroll
    for (int i = 0; i < 2; ++i) dst[tx + i*256] = f2b(s1[tx + i*256]);
#pragma unroll
    for (int i = 0; i < 4; ++i) dst[E_ + tx + i*256] = f2b(s2[tx + i*256]);
    if (tx == 0) bp[p] = bih[orig] + bhh[orig];
}

__global__ void prep_xe(const int* __restrict__ x, const float* __restrict__ emb,
                        unsigned short* __restrict__ xe) {
    int bid = blockIdx.x;
    int t = bid >> 6, b = bid & 63;
    int idx = x[b * T_ + t];
    const float* src = emb + (size_t)idx * E_;
    unsigned short* dst = xe + ((size_t)t * B_ + b) * E_;
    int tx = threadIdx.x;
    dst[tx] = f2b(src[tx]);
    dst[tx + 256] = f2b(src[tx + 256]);
}

__global__ void prep_h(const float* __restrict__ h0, unsigned short* __restrict__ hb) {
    int b = blockIdx.x;
#pragma unroll
    for (int i = 0; i < 4; ++i) {
        int j = threadIdx.x + i*256;
        hb[(size_t)b * H_ + j] = f2b(h0[(size_t)b * H_ + j]);
    }
}

// v5 = v2 + drain-free release. 256 WGs = 4 groups of 64 (g = wg&3 owns rows
// [16g,16g+16); s = wg>>2 -> 64 gate cols). 4 waves (ch, kh). Weights in
// AGPRs. h(t) bypass-stored bf16 into hbt[t] (fresh addresses); consumers
// plain cached loads (L2-deduped). out[] + xe(t+1) prefetch float across the
// poll AND across the release: release is a raw s_barrier (no vmcnt drain),
// so they complete under the next step's MFMA phase. LDS dead-flag escape.
__global__ __launch_bounds__(256, 1)
void lstm_v5(const unsigned short* __restrict__ xe,
             const unsigned short* __restrict__ Wc,
             const float* __restrict__ bp,
             const float* __restrict__ c0,
             const unsigned short* __restrict__ hb0,
             unsigned short* __restrict__ hbt,
             float* __restrict__ out,
             int* __restrict__ flags) {
    __shared__ float gpart[2][16][68];
    __shared__ int sh_dead;

    const int tid = threadIdx.x;
    const int wg  = blockIdx.x;
    const int g   = wg & 3;
    const int s   = wg >> 2;
    const int w = tid >> 6, l = tid & 63;
    const int ch = w >> 1, kh = w & 1;
    const int lc = l & 15;
    const int lk = (l >> 4) << 3;

    if (tid == 0) sh_dead = 0;

    i32x4 wreg0[24], wreg1[24];
    {
        const unsigned short* wrow0 = Wc + (size_t)((s << 6) + (ch << 5) + lc) * KTOT;
        const unsigned short* wrow1 = wrow0 + (size_t)16 * KTOT;
#pragma unroll
        for (int j = 0; j < 8; ++j) {
            int k = (kh << 8) + j * 32 + lk;
            wreg0[j] = *(const i32x4*)(wrow0 + k);
            wreg1[j] = *(const i32x4*)(wrow1 + k);
        }
#pragma unroll
        for (int j = 0; j < 16; ++j) {
            int k = 512 + (kh << 9) + j * 32 + lk;
            wreg0[8 + j] = *(const i32x4*)(wrow0 + k);
            wreg1[8 + j] = *(const i32x4*)(wrow1 + k);
        }
    }

    const int brow = (g << 4) + lc;

    const int b_c = tid >> 4, hl_c = tid & 15;
    const int bglob = (g << 4) + b_c;
    const int hdim = (s << 4) + hl_c;
    float c = c0[(size_t)bglob * H_ + hdim];
    const float bi  = bp[(s << 6) + hl_c];
    const float bf_ = bp[(s << 6) + 16 + hl_c];
    const float bg  = bp[(s << 6) + 32 + hl_c];
    const float bo  = bp[(s << 6) + 48 + hl_c];

    int* subc = &flags[g << 10];         // 8 sub-counters, 128 B apart
    const int si = (wg >> 2) & 7;

    i32x4 a[24];
    {   // t=0 xe frags
        const unsigned short* xp = xe + ((size_t)brow) * E_ + (kh << 8) + lk;
#pragma unroll
        for (int j = 0; j < 8; ++j) a[j] = *(const i32x4*)(xp + j * 32);
    }

    for (int t = 0; t < T_; ++t) {
        // ---- h frags: bf16, uniform layout (hb0 at t=0, hbt[t-1] after) ----
        {
            const unsigned short* hsrc =
                (t == 0 ? hb0 : hbt + (size_t)(t - 1) * (B_ * H_))
                + (size_t)brow * H_ + (kh << 9) + lk;
#pragma unroll
            for (int j = 0; j < 16; ++j) a[8 + j] = *(const i32x4*)(hsrc + j * 32);
        }

        f32x4 acc0 = {0.f, 0.f, 0.f, 0.f};
        f32x4 acc1 = {0.f, 0.f, 0.f, 0.f};
        // xe MFMAs first (prefetched regs) overlap the in-flight h loads.
        asm volatile("s_nop 3\n\tv_mfma_f32_16x16x32_bf16 %0, %1, %2, %0"
                     : "+v"(acc0) : "v"(a[0]), "a"(wreg0[0]));
        asm volatile("s_nop 3\n\tv_mfma_f32_16x16x32_bf16 %0, %1, %2, %0"
                     : "+v"(acc1) : "v"(a[0]), "a"(wreg1[0]));
#pragma unroll
        for (int j = 1; j < 24; ++j) {
            asm volatile("s_nop 1\n\tv_mfma_f32_16x16x32_bf16 %0, %1, %2, %0"
                         : "+v"(acc0) : "v"(a[j]), "a"(wreg0[j]));
            asm volatile("s_nop 1\n\tv_mfma_f32_16x16x32_bf16 %0, %1, %2, %0"
                         : "+v"(acc1) : "v"(a[j]), "a"(wreg1[j]));
        }
        asm volatile("s_nop 7\n\ts_nop 7\n\ts_nop 7"
                     : "+v"(acc0), "+v"(acc1) :: "memory");
        {
            const int grow = (l >> 4) << 2;
            const int cb = (ch << 5) + lc;
#pragma unroll
            for (int j = 0; j < 4; ++j) {
                gpart[kh][grow + j][cb]      = acc0[j];
                gpart[kh][grow + j][cb + 16] = acc1[j];
            }
        }
        __syncthreads();

        // ---- LSTM cell ----
        float hv;
        {
            float xi = gpart[0][b_c][hl_c]      + gpart[1][b_c][hl_c]      + bi;
            float xf = gpart[0][b_c][16 + hl_c] + gpart[1][b_c][16 + hl_c] + bf_;
            float xg = gpart[0][b_c][32 + hl_c] + gpart[1][b_c][32 + hl_c] + bg;
            float xo = gpart[0][b_c][48 + hl_c] + gpart[1][b_c][48 + hl_c] + bo;
            float iv = 1.f / (1.f + __expf(-xi));
            float fv = 1.f / (1.f + __expf(-xf));
            float eg = __expf(2.f * fminf(fmaxf(xg, -15.f), 15.f));
            float gv = (eg - 1.f) / (eg + 1.f);
            float ov = 1.f / (1.f + __expf(-xo));
            c = fv * c + iv * gv;
            float ec = __expf(2.f * fminf(fmaxf(c, -15.f), 15.f));
            float th = (ec - 1.f) / (ec + 1.f);
            hv = ov * th;
        }
        const size_t oidx = ((size_t)bglob * T_ + t) * H_ + hdim;

        if (t == T_ - 1) {
            __builtin_nontemporal_store(hv, &out[oidx]);
            break;
        }

        // bf16 h broadcast: bypass store to coherent point (MFMA-ready payload)
        {
            unsigned long long hdst = (unsigned long long)
                (hbt + (size_t)t * (B_ * H_) + (size_t)bglob * H_ + hdim);
            unsigned hval = (unsigned)f2b(hv);
            asm volatile("global_store_short %0, %1, off sc0 sc1"
                         :: "v"(hdst), "v"(hval) : "memory");
        }
        asm volatile("s_waitcnt vmcnt(0)" ::: "memory");   // h store acked
        __syncthreads();                                   // all waves acked
        if (tid == 0)
            __hip_atomic_fetch_add(&subc[si << 5], 1, __ATOMIC_RELAXED,
                                   __HIP_MEMORY_SCOPE_AGENT);
        // off-critical-path work floats across the poll AND the release:
        __builtin_nontemporal_store(hv, &out[oidx]);       // f32 output
        {                                                  // xe(t+1) prefetch
            const unsigned short* xp = xe + ((size_t)(t + 1) * B_ + brow) * E_
                                          + (kh << 8) + lk;
#pragma unroll
            for (int j = 0; j < 8; ++j) a[j] = *(const i32x4*)(xp + j * 32);
        }
        if (w == 0) {                                      // busy poll, no sleep
            int dead = 0;
            const int tgt = (t + 1) << 3;                  // 8*(t+1), monotonic
            unsigned spin = 0;
            for (;;) {
                int v = (l < 8)
                    ? __hip_atomic_load(&subc[l << 5], __ATOMIC_RELAXED,
                                        __HIP_MEMORY_SCOPE_AGENT)
                    : tgt;
                if (__all(v >= tgt)) break;
                if (++spin > (1u << 17)) { dead = 1; break; }  // escape, no hang
            }
            if (l == 0 && dead) *(volatile int*)&sh_dead = 1;
        }
        // ---- drain-free release: raw barrier, no vmcnt(0) ----
        asm volatile("s_waitcnt lgkmcnt(0)" ::: "memory"); // dead-flag ds_write done
        __builtin_amdgcn_s_barrier();
        asm volatile("" ::: "memory");   // next-step h pulls can't hoist above
        if (*(volatile int*)&sh_dead) break;               // uniform exit
    }
}

extern "C" void kernel_launch(void* const* d_in, const int* in_sizes, int n_in,
                              void* d_out, int out_size, void* d_ws, size_t ws_size,
                              hipStream_t stream) {
    const int*   x   = (const int*)  d_in[0];
    const float* emb = (const float*)d_in[1];
    const float* wih = (const float*)d_in[2];
    const float* whh = (const float*)d_in[3];
    const float* bih = (const float*)d_in[4];
    const float* bhh = (const float*)d_in[5];
    const float* h0  = (const float*)d_in[6];
    const float* c0  = (const float*)d_in[7];
    float* out = (float*)d_out;
    char* ws = (char*)d_ws;

    unsigned short* xe  = (unsigned short*)(ws + OFF_XE);
    unsigned short* Wc  = (unsigned short*)(ws + OFF_WC);
    float*          bp  = (float*)(ws + OFF_BIAS);
    unsigned short* hb0 = (unsigned short*)(ws + OFF_H0);
    int*            flg = (int*)(ws + OFF_FLAGS);
    unsigned short* hbt = (unsigned short*)(ws + OFF_HBT);

    (void)hipMemsetAsync(flg, 0, 4096 * sizeof(int), stream);
    prep_w <<<dim3(G4_),   dim3(256), 0, stream>>>(wih, whh, bih, bhh, Wc, bp);
    prep_xe<<<dim3(B_*T_), dim3(256), 0, stream>>>(x, emb, xe);
    prep_h <<<dim3(B_),    dim3(256), 0, stream>>>(h0, hb0);

    lstm_v5<<<dim3(NWG), dim3(256), 0, stream>>>(xe, Wc, bp, c0, hb0, hbt, out, flg);
}